// Round 15
// baseline (380.116 us; speedup 1.0000x reference)
//
#include <hip/hip_runtime.h>
#include <stdint.h>

#define TPB 256
#define BM 64
#define CTXD 256
#define HID 128
#define TSTEPS 48
#define DTC (1.0f/30.0f)

typedef short short8 __attribute__((ext_vector_type(8)));
typedef float f32x4 __attribute__((ext_vector_type(4)));
typedef float f32x2 __attribute__((ext_vector_type(2)));

// ---------------- LDS layout (bytes) — 1 block/CU (grid 256), no co-residency needed ----------------
// weight tiles: row stride 256B, XOR swizzle byte ^= (row&15)<<4 -> conflict-free b128.
#define OFF_WN   0        // W_hh N-gate bf16 [128][128]
#define OFF_WZ   32768    // W_hh Z-gate bf16 [128][128]
#define OFF_W1   65536    // W1 bf16 [64][128]
#define OFF_HB   81920    // per-wave h buffer: + w*4096 + l15*256, col ^ (l15<<4)   (16 KB)
#define OFF_WD   98304    // 6 f32[128] tables: wdr0,wdr1,wdz0,wdz1,wdn0,wdn1
#define OFF_BHN  101376   // bhh_n f32[128]
#define OFF_TB1  101888   // b1 f32[64]
#define OFF_TW2  102144   // W2 f32[2][64]
#define OFF_CTX  102656   // ctx bf16 per wave: + w*8192 + r*512, col ^ (r<<4)       (32 KB)
#define LDS_BYTES 135424

__device__ __forceinline__ uint32_t cvtpk_bf16(float lo, float hi) {
    uint32_t r;
    asm("v_cvt_pk_bf16_f32 %0, %1, %2" : "=v"(r) : "v"(lo), "v"(hi));
    return r;
}
__device__ __forceinline__ uint32_t pkh2(float a, float b) {
    union { _Float16 h[2]; uint32_t u; } v;
    v.h[0] = (_Float16)a; v.h[1] = (_Float16)b; return v.u;
}
__device__ __forceinline__ float h2lo(uint32_t u) {
    union { uint32_t u; _Float16 h[2]; } v; v.u = u; return (float)v.h[0];
}
__device__ __forceinline__ float h2hi(uint32_t u) {
    union { uint32_t u; _Float16 h[2]; } v; v.u = u; return (float)v.h[1];
}
__device__ __forceinline__ float fsigm(float x) {
    return __builtin_amdgcn_rcpf(1.0f + __expf(-x));
}
__device__ __forceinline__ float ftanhf(float x) {
    return fmaf(-2.0f, __builtin_amdgcn_rcpf(1.0f + __expf(2.0f * x)), 1.0f);
}
__device__ __forceinline__ short8 ldA8(const float* src) {
    f32x2 v0 = *(const f32x2*)(src + 0);
    f32x2 v1 = *(const f32x2*)(src + 2);
    f32x2 v2 = *(const f32x2*)(src + 4);
    f32x2 v3 = *(const f32x2*)(src + 6);
    union { short8 s; uint32_t u[4]; } r;
    r.u[0] = cvtpk_bf16(v0.x, v0.y);
    r.u[1] = cvtpk_bf16(v1.x, v1.y);
    r.u[2] = cvtpk_bf16(v2.x, v2.y);
    r.u[3] = cvtpk_bf16(v3.x, v3.y);
    return r.s;
}

// BARRIER-FREE DESIGN (R14 conclusion): each wave owns 16 batch rows end-to-end
// (all 384 GRU gate rows + full MLP). MFMA total per row is distribution-
// invariant, so this costs no extra MFMAs but removes BOTH per-step barriers:
// h transpose goes through a wave-private LDS buffer (same-wave write->read,
// lgkmcnt only), delta via intra-wave shfl_xor. 1024 waves = 1 wave/SIMD at
// launch_bounds(256,1) (512-reg budget, R1-proven). W_R in registers;
// W_Z/W_N/W1 + f32 gate tables in LDS (anti-LICM opaque offset so the ~80
// loop-invariant b128s can't be hoisted into registers).
__global__ __launch_bounds__(TPB, 1)
void dd_kernel(const float* __restrict__ ctx, const float* __restrict__ lv,
               const float* __restrict__ Winit, const float* __restrict__ binit,
               const float* __restrict__ Wih, const float* __restrict__ bih,
               const float* __restrict__ Whh, const float* __restrict__ bhh,
               const float* __restrict__ W1, const float* __restrict__ b1,
               const float* __restrict__ W2, const float* __restrict__ b2,
               float* __restrict__ out)
{
    extern __shared__ char smem[];
    const int tid  = threadIdx.x;
    const int w    = tid >> 6;          // wave 0..3; owns rows [row0+16w, +16)
    const int lane = tid & 63;
    const int g    = (lane >> 4) & 3;
    const int l15  = lane & 15;
    const int row0 = blockIdx.x * BM;
    const int myrow = row0 + 16 * w + l15;
    const int swz  = l15 << 4;

    // ---------------- stage LDS ----------------
    for (int p = tid; p < 128 * 64; p += TPB) {           // W_hh N rows 256..383
        int u = p >> 6, kp = p & 63;
        f32x2 v = *(const f32x2*)(Whh + (size_t)(256 + u) * HID + 2 * kp);
        *(uint32_t*)(smem + OFF_WN + u * 256 + ((4 * kp) ^ ((u & 15) << 4))) = cvtpk_bf16(v.x, v.y);
    }
    for (int p = tid; p < 128 * 64; p += TPB) {           // W_hh Z rows 128..255
        int u = p >> 6, kp = p & 63;
        f32x2 v = *(const f32x2*)(Whh + (size_t)(128 + u) * HID + 2 * kp);
        *(uint32_t*)(smem + OFF_WZ + u * 256 + ((4 * kp) ^ ((u & 15) << 4))) = cvtpk_bf16(v.x, v.y);
    }
    for (int p = tid; p < 64 * 64; p += TPB) {            // W1
        int u = p >> 6, kp = p & 63;
        f32x2 v = *(const f32x2*)(W1 + u * HID + 2 * kp);
        *(uint32_t*)(smem + OFF_W1 + u * 256 + ((4 * kp) ^ ((u & 15) << 4))) = cvtpk_bf16(v.x, v.y);
    }
    for (int p = tid; p < 64 * 128; p += TPB) {           // ctx, per-wave regions
        int r = p >> 7, kp = p & 127;
        f32x2 v = *(const f32x2*)(ctx + (size_t)(row0 + r) * CTXD + 2 * kp);
        *(uint32_t*)(smem + OFF_CTX + (r >> 4) * 8192 + (r & 15) * 512 + ((4 * kp) ^ ((r & 15) << 4))) = cvtpk_bf16(v.x, v.y);
    }
    if (tid < 128) {                                      // f32 tables
        int u = tid;
        ((float*)(smem + OFF_WD +    0))[u] = Wih[(size_t)u * 258 + 0];
        ((float*)(smem + OFF_WD +  512))[u] = Wih[(size_t)u * 258 + 1];
        ((float*)(smem + OFF_WD + 1024))[u] = Wih[(size_t)(128 + u) * 258 + 0];
        ((float*)(smem + OFF_WD + 1536))[u] = Wih[(size_t)(128 + u) * 258 + 1];
        ((float*)(smem + OFF_WD + 2048))[u] = Wih[(size_t)(256 + u) * 258 + 0];
        ((float*)(smem + OFF_WD + 2560))[u] = Wih[(size_t)(256 + u) * 258 + 1];
        ((float*)(smem + OFF_BHN))[u] = bhh[256 + u];
        ((float*)(smem + OFF_TW2))[u] = W2[u];
    }
    if (tid < 64) ((float*)(smem + OFF_TB1))[tid] = b1[tid];

    const float b2c0 = b2[0], b2c1 = b2[1];
    float dx, dy, pos0v, pos1v;
    {
        f32x2 v = *(const f32x2*)(lv + (size_t)myrow * 2);
        dx = v.x * DTC; dy = v.y * DTC; pos0v = 0.f; pos1v = 0.f;
    }

    __syncthreads();   // staging done — the ONLY block barrier

    // ---------------- Phase A: gi (24 tiles) + h0 (8 tiles), one-time ----------------
    f32x4 zero4 = {0.f, 0.f, 0.f, 0.f};
    f32x4 accR[8], accZ[8], accN[8], accH[8];
#pragma unroll
    for (int T = 0; T < 8; ++T) { accR[T] = zero4; accZ[T] = zero4; accN[T] = zero4; accH[T] = zero4; }

    const int ctxb = OFF_CTX + w * 8192 + l15 * 512;
    for (int kk = 0; kk < 8; ++kk) {
        short8 bf = *(const short8*)(smem + ctxb + ((64 * kk + 16 * g) ^ swz));
#pragma unroll
        for (int T = 0; T < 8; ++T) {
            const size_t uT = 16 * T + l15;
            short8 aR8 = ldA8(Wih + uT * 258 + 2 + 32 * kk + 8 * g);
            short8 aZ8 = ldA8(Wih + (128 + uT) * 258 + 2 + 32 * kk + 8 * g);
            short8 aN8 = ldA8(Wih + (256 + uT) * 258 + 2 + 32 * kk + 8 * g);
            short8 aH8 = ldA8(Winit + uT * 256 + 32 * kk + 8 * g);
            accR[T] = __builtin_amdgcn_mfma_f32_16x16x32_bf16(aR8, bf, accR[T], 0, 0, 0);
            accZ[T] = __builtin_amdgcn_mfma_f32_16x16x32_bf16(aZ8, bf, accZ[T], 0, 0, 0);
            accN[T] = __builtin_amdgcn_mfma_f32_16x16x32_bf16(aN8, bf, accN[T], 0, 0, 0);
            accH[T] = __builtin_amdgcn_mfma_f32_16x16x32_bf16(aH8, bf, accH[T], 0, 0, 0);
        }
    }

    // finalize: giR/giZ f32 (MFMA C-init), giN f16-packed, h0 -> hm (f32 master)
    f32x4 giR[8], giZ[8];
    uint2 giNp[8];
    float hm[8][4];
#pragma unroll
    for (int T = 0; T < 8; ++T) {
        float gn[4];
#pragma unroll
        for (int r = 0; r < 4; ++r) {
            int u = 16 * T + 4 * g + r;
            giR[T][r] = accR[T][r] + bih[u] + bhh[u];
            giZ[T][r] = accZ[T][r] + bih[128 + u] + bhh[128 + u];
            gn[r]     = accN[T][r] + bih[256 + u];
            hm[T][r]  = ftanhf(accH[T][r] + binit[u]);
        }
        giNp[T].x = pkh2(gn[0], gn[1]);
        giNp[T].y = pkh2(gn[2], gn[3]);
    }

    // W_R fragments register-resident (loaded after phase A; loop-only lifetime)
    short8 wfr[8][4];
#pragma unroll
    for (int T = 0; T < 8; ++T)
#pragma unroll
        for (int kk = 0; kk < 4; ++kk)
            wfr[T][kk] = ldA8(Whh + (size_t)(16 * T + l15) * HID + 32 * kk + 8 * g);

    // write h0 into wave-private buffer, read B-frags (same-wave: lgkmcnt only)
    const int hb = OFF_HB + w * 4096 + l15 * 256;
#pragma unroll
    for (int T = 0; T < 8; ++T) {
        uint2 pk;
        pk.x = cvtpk_bf16(hm[T][0], hm[T][1]);
        pk.y = cvtpk_bf16(hm[T][2], hm[T][3]);
        *(uint2*)(smem + hb + ((32 * T + 8 * g) ^ swz)) = pk;
    }
    short8 hf[4];
#pragma unroll
    for (int kk = 0; kk < 4; ++kk)
        hf[kk] = *(const short8*)(smem + hb + ((64 * kk + 16 * g) ^ swz));

    // ---------------- 48-step recurrence — NO BARRIERS ----------------
    for (int t = 0; t < TSTEPS; ++t) {
        // anti-LICM: opaque zero offset makes read-only LDS loads loop-variant
        int tdep = 0;
        asm volatile("" : "+v"(tdep));
        const char* sm = smem + tdep;

        // GRU: per unit-tile T — preacts then gates (gates need dx,dy from prev iter)
#pragma unroll
        for (int T = 0; T < 8; ++T) {
            const int tb = 64 * T + 16 * g;       // byte offset into f32[128] tables
            f32x4 aR = giR[T], aZ = giZ[T];
            f32x4 aN = *(const f32x4*)(sm + OFF_BHN + tb);
#pragma unroll
            for (int kk = 0; kk < 4; ++kk) {
                const int cx = (64 * kk + 16 * g) ^ swz;
                short8 fZ = *(const short8*)(sm + OFF_WZ + (16 * T + l15) * 256 + cx);
                short8 fN = *(const short8*)(sm + OFF_WN + (16 * T + l15) * 256 + cx);
                aR = __builtin_amdgcn_mfma_f32_16x16x32_bf16(wfr[T][kk], hf[kk], aR, 0, 0, 0);
                aZ = __builtin_amdgcn_mfma_f32_16x16x32_bf16(fZ, hf[kk], aZ, 0, 0, 0);
                aN = __builtin_amdgcn_mfma_f32_16x16x32_bf16(fN, hf[kk], aN, 0, 0, 0);
            }
            f32x4 wr0 = *(const f32x4*)(sm + OFF_WD +    0 + tb);
            f32x4 wr1 = *(const f32x4*)(sm + OFF_WD +  512 + tb);
            f32x4 wz0 = *(const f32x4*)(sm + OFF_WD + 1024 + tb);
            f32x4 wz1 = *(const f32x4*)(sm + OFF_WD + 1536 + tb);
            f32x4 wn0 = *(const f32x4*)(sm + OFF_WD + 2048 + tb);
            f32x4 wn1 = *(const f32x4*)(sm + OFF_WD + 2560 + tb);
#pragma unroll
            for (int r = 0; r < 4; ++r) {
                float rr  = fsigm(fmaf(dy, wr1[r], fmaf(dx, wr0[r], aR[r])));
                float zz  = fsigm(fmaf(dy, wz1[r], fmaf(dx, wz0[r], aZ[r])));
                float gnv = (r & 1) ? h2hi(((const uint32_t*)&giNp[T])[r >> 1])
                                    : h2lo(((const uint32_t*)&giNp[T])[r >> 1]);
                float inn = fmaf(dy, wn1[r], fmaf(dx, wn0[r], gnv));
                float nn  = ftanhf(fmaf(rr, aN[r], inn));
                hm[T][r]  = fmaf(zz, hm[T][r] - nn, nn);
            }
            uint2 pk;
            pk.x = cvtpk_bf16(hm[T][0], hm[T][1]);
            pk.y = cvtpk_bf16(hm[T][2], hm[T][3]);
            *(uint2*)(smem + hb + ((32 * T + 8 * g) ^ swz)) = pk;
        }
        // h_{t+1} B-frags (same-wave RAW; compiler inserts lgkmcnt)
#pragma unroll
        for (int kk = 0; kk < 4; ++kk)
            hf[kk] = *(const short8*)(smem + hb + ((64 * kk + 16 * g) ^ swz));

        // MLP(h_{t+1}) -> delta (intra-wave reduce, no barrier)
        f32x4 a1[4] = {zero4, zero4, zero4, zero4};
#pragma unroll
        for (int J = 0; J < 4; ++J)
#pragma unroll
            for (int kk = 0; kk < 4; ++kk) {
                short8 wf = *(const short8*)(sm + OFF_W1 + (16 * J + l15) * 256 + ((64 * kk + 16 * g) ^ swz));
                a1[J] = __builtin_amdgcn_mfma_f32_16x16x32_bf16(wf, hf[kk], a1[J], 0, 0, 0);
            }
        float s0 = 0.f, s1 = 0.f;
#pragma unroll
        for (int J = 0; J < 4; ++J) {
            const int tb = 64 * J + 16 * g;
            f32x4 b1v = *(const f32x4*)(sm + OFF_TB1 + tb);
            f32x4 w2a = *(const f32x4*)(sm + OFF_TW2 + tb);
            f32x4 w2b = *(const f32x4*)(sm + OFF_TW2 + 256 + tb);
#pragma unroll
            for (int r = 0; r < 4; ++r) {
                float hv = fmaxf(a1[J][r] + b1v[r], 0.f);
                s0 = fmaf(hv, w2a[r], s0);
                s1 = fmaf(hv, w2b[r], s1);
            }
        }
        s0 += __shfl_xor(s0, 16, 64); s0 += __shfl_xor(s0, 32, 64);
        s1 += __shfl_xor(s1, 16, 64); s1 += __shfl_xor(s1, 32, 64);
        s0 += b2c0; s1 += b2c1;
        dx = s0; dy = s1;
        pos0v += s0; pos1v += s1;
        if (lane < 16) {
            f32x2 o2; o2.x = pos0v; o2.y = pos1v;
            *(f32x2*)(out + (size_t)myrow * (TSTEPS * 2) + 2 * t) = o2;
        }
    }
}

extern "C" void kernel_launch(void* const* d_in, const int* in_sizes, int n_in,
                              void* d_out, int out_size, void* d_ws, size_t ws_size,
                              hipStream_t stream) {
    (void)in_sizes; (void)n_in; (void)d_ws; (void)ws_size; (void)out_size;
    const float* ctx   = (const float*)d_in[0];
    const float* lv    = (const float*)d_in[1];
    const float* Winit = (const float*)d_in[2];
    const float* binit = (const float*)d_in[3];
    const float* Wih   = (const float*)d_in[4];
    const float* bih   = (const float*)d_in[5];
    const float* Whh   = (const float*)d_in[6];
    const float* bhh   = (const float*)d_in[7];
    const float* W1    = (const float*)d_in[8];
    const float* b1    = (const float*)d_in[9];
    const float* W2    = (const float*)d_in[10];
    const float* b2    = (const float*)d_in[11];
    float* out = (float*)d_out;

    hipFuncSetAttribute(reinterpret_cast<const void*>(dd_kernel),
                        hipFuncAttributeMaxDynamicSharedMemorySize, LDS_BYTES);
    dd_kernel<<<16384 / BM, TPB, LDS_BYTES, stream>>>(
        ctx, lv, Winit, binit, Wih, bih, Whh, bhh, W1, b1, W2, b2, out);
}

// Round 16
// 235.685 us; speedup vs baseline: 1.6128x; 1.6128x over previous
//
#include <hip/hip_runtime.h>
#include <stdint.h>

#define TPB 1024
#define BM 32
#define CTXD 256
#define HID 128
#define TSTEPS 48
#define DTC (1.0f/30.0f)

typedef short short8 __attribute__((ext_vector_type(8)));
typedef float f32x4 __attribute__((ext_vector_type(4)));
typedef float f32x2 __attribute__((ext_vector_type(2)));

// ---------------- LDS layout (bytes) — 141 KB, 1 block/CU, 16 waves ----------------
// weight/h tiles: row stride 256B, XOR swizzle byte ^= (row&15)<<4 -> conflict-free b128.
#define OFF_WR   0        // W_hh R bf16 [128][128]
#define OFF_WZ   32768    // W_hh Z
#define OFF_WN   65536    // W_hh N
#define OFF_W1   98304    // W1 bf16 [64][128]
#define OFF_H    114688   // loop: 2 x h bf16 [32][256B] (8K each); phase A: ctx [32][512B] (16K)
#define HBUFSZ   8192
#define CSTRIDE  512
#define OFF_GIN  131072   // gi_n f16-packed per-thread [1024][8B] (own-slot)
#define OFF_WD   139264   // 6 f32[128] tables: wdr0,wdr1,wdz0,wdz1,wdn0,wdn1
#define OFF_BHN  142336   // bhh_n f32[128]
#define OFF_TB1  142848   // b1 f32[64]
#define OFF_TW2  143104   // W2 f32[2][64]
#define OFF_PART 143616   // delta partials f32 [2 mt][16 l15][4 jt][2] = 1024
#define LDS_BYTES 144640

__device__ __forceinline__ uint32_t cvtpk_bf16(float lo, float hi) {
    uint32_t r;
    asm("v_cvt_pk_bf16_f32 %0, %1, %2" : "=v"(r) : "v"(lo), "v"(hi));
    return r;
}
__device__ __forceinline__ uint32_t pkh2(float a, float b) {
    union { _Float16 h[2]; uint32_t u; } v;
    v.h[0] = (_Float16)a; v.h[1] = (_Float16)b; return v.u;
}
__device__ __forceinline__ float h2lo(uint32_t u) {
    union { uint32_t u; _Float16 h[2]; } v; v.u = u; return (float)v.h[0];
}
__device__ __forceinline__ float h2hi(uint32_t u) {
    union { uint32_t u; _Float16 h[2]; } v; v.u = u; return (float)v.h[1];
}
__device__ __forceinline__ float fsigm(float x) {
    return __builtin_amdgcn_rcpf(1.0f + __expf(-x));
}
__device__ __forceinline__ float ftanhf(float x) {
    return fmaf(-2.0f, __builtin_amdgcn_rcpf(1.0f + __expf(2.0f * x)), 1.0f);
}
__device__ __forceinline__ short8 ldA8(const float* src) {
    f32x2 v0 = *(const f32x2*)(src + 0);
    f32x2 v1 = *(const f32x2*)(src + 2);
    f32x2 v2 = *(const f32x2*)(src + 4);
    f32x2 v3 = *(const f32x2*)(src + 6);
    union { short8 s; uint32_t u[4]; } r;
    r.u[0] = cvtpk_bf16(v0.x, v0.y);
    r.u[1] = cvtpk_bf16(v1.x, v1.y);
    r.u[2] = cvtpk_bf16(v2.x, v2.y);
    r.u[3] = cvtpk_bf16(v3.x, v3.y);
    return r.s;
}

// OCCUPANCY MAP (R9-R15): 4 waves/CU latency-bound (380us), 8 waves lockstep
// (204us), 16 waves with ~135-reg set spills (280-300us). This kernel claims
// the missing cell: 16 waves/CU with a TRUE <=128-reg working set — ALL
// weights in LDS (112KB), each wave owns unit-tile x ONE row-tile, so live
// state ~= 55-64 VGPR + 16 AGPR. TPB=1024 (the 64/64 split is now sufficient,
// not a constraint). Anti-LICM opaque base stops the compiler hoisting the
// 12 loop-invariant weight frags (96 regs) back into registers.
__global__ __launch_bounds__(TPB, 1)
void dd_kernel(const float* __restrict__ ctx, const float* __restrict__ lv,
               const float* __restrict__ Winit, const float* __restrict__ binit,
               const float* __restrict__ Wih, const float* __restrict__ bih,
               const float* __restrict__ Whh, const float* __restrict__ bhh,
               const float* __restrict__ W1, const float* __restrict__ b1,
               const float* __restrict__ W2, const float* __restrict__ b2,
               float* __restrict__ out)
{
    extern __shared__ char smem[];
    const int tid  = threadIdx.x;
    const int w    = tid >> 6;          // wave 0..15
    const int lane = tid & 63;
    const int g    = (lane >> 4) & 3;
    const int l15  = lane & 15;
    const int row0 = blockIdx.x * BM;
    const int wsub = w & 7;             // GRU unit-tile: units 16*wsub..+15
    const int mt   = w >> 3;            // row-tile 0/1: rows row0+16*mt..+15
    const int jt   = w & 3;             // MLP hidden tile (waves 0..7 only)
    const int mrow = (w >> 2) & 1;      // MLP row-tile   (waves 0..7 only)
    const int swz  = l15 << 4;

    // ---------------- stage LDS ----------------
    for (int p = tid; p < 128 * 64; p += TPB) {           // W_hh R
        int u = p >> 6, kp = p & 63;
        f32x2 v = *(const f32x2*)(Whh + (size_t)u * HID + 2 * kp);
        *(uint32_t*)(smem + OFF_WR + u * 256 + ((4 * kp) ^ ((u & 15) << 4))) = cvtpk_bf16(v.x, v.y);
    }
    for (int p = tid; p < 128 * 64; p += TPB) {           // W_hh Z
        int u = p >> 6, kp = p & 63;
        f32x2 v = *(const f32x2*)(Whh + (size_t)(128 + u) * HID + 2 * kp);
        *(uint32_t*)(smem + OFF_WZ + u * 256 + ((4 * kp) ^ ((u & 15) << 4))) = cvtpk_bf16(v.x, v.y);
    }
    for (int p = tid; p < 128 * 64; p += TPB) {           // W_hh N
        int u = p >> 6, kp = p & 63;
        f32x2 v = *(const f32x2*)(Whh + (size_t)(256 + u) * HID + 2 * kp);
        *(uint32_t*)(smem + OFF_WN + u * 256 + ((4 * kp) ^ ((u & 15) << 4))) = cvtpk_bf16(v.x, v.y);
    }
    for (int p = tid; p < 64 * 64; p += TPB) {            // W1
        int u = p >> 6, kp = p & 63;
        f32x2 v = *(const f32x2*)(W1 + u * HID + 2 * kp);
        *(uint32_t*)(smem + OFF_W1 + u * 256 + ((4 * kp) ^ ((u & 15) << 4))) = cvtpk_bf16(v.x, v.y);
    }
    for (int p = tid; p < 32 * 128; p += TPB) {           // ctx (phase A, stride 512)
        int r = p >> 7, kp = p & 127;
        f32x2 v = *(const f32x2*)(ctx + (size_t)(row0 + r) * CTXD + 2 * kp);
        *(uint32_t*)(smem + OFF_H + r * CSTRIDE + ((4 * kp) ^ ((r & 15) << 4))) = cvtpk_bf16(v.x, v.y);
    }
    if (tid < 128) {                                      // f32 tables
        int u = tid;
        ((float*)(smem + OFF_WD +    0))[u] = Wih[(size_t)u * 258 + 0];
        ((float*)(smem + OFF_WD +  512))[u] = Wih[(size_t)u * 258 + 1];
        ((float*)(smem + OFF_WD + 1024))[u] = Wih[(size_t)(128 + u) * 258 + 0];
        ((float*)(smem + OFF_WD + 1536))[u] = Wih[(size_t)(128 + u) * 258 + 1];
        ((float*)(smem + OFF_WD + 2048))[u] = Wih[(size_t)(256 + u) * 258 + 0];
        ((float*)(smem + OFF_WD + 2560))[u] = Wih[(size_t)(256 + u) * 258 + 1];
        ((float*)(smem + OFF_BHN))[u] = bhh[256 + u];
        ((float*)(smem + OFF_TW2))[u] = W2[u];
    }
    if (tid < 64) ((float*)(smem + OFF_TB1))[tid] = b1[tid];

    const float b2c0 = b2[0], b2c1 = b2[1];
    float dx, dy, pos0v, pos1v;
    {
        f32x2 v = *(const f32x2*)(lv + (size_t)(row0 + 16 * mt + l15) * 2);
        dx = v.x * DTC; dy = v.y * DTC; pos0v = 0.f; pos1v = 0.f;
    }

    __syncthreads();

    // ---------------- Phase A: gi tile + h0 (unit-tile wsub x row-tile mt) ----------------
    f32x4 zero4 = {0.f, 0.f, 0.f, 0.f};
    f32x4 accR = zero4, accZ = zero4, accN = zero4, accH = zero4;
    const int u16 = 16 * wsub + l15;
    for (int kk = 0; kk < 8; ++kk) {
        short8 bf = *(const short8*)(smem + OFF_H + (16 * mt + l15) * CSTRIDE + ((64 * kk + 16 * g) ^ swz));
        short8 afR = ldA8(Wih + (size_t)u16 * 258 + 2 + 32 * kk + 8 * g);
        short8 afZ = ldA8(Wih + (size_t)(128 + u16) * 258 + 2 + 32 * kk + 8 * g);
        short8 afN = ldA8(Wih + (size_t)(256 + u16) * 258 + 2 + 32 * kk + 8 * g);
        short8 afH = ldA8(Winit + (size_t)u16 * 256 + 32 * kk + 8 * g);
        accR = __builtin_amdgcn_mfma_f32_16x16x32_bf16(afR, bf, accR, 0, 0, 0);
        accZ = __builtin_amdgcn_mfma_f32_16x16x32_bf16(afZ, bf, accZ, 0, 0, 0);
        accN = __builtin_amdgcn_mfma_f32_16x16x32_bf16(afN, bf, accN, 0, 0, 0);
        accH = __builtin_amdgcn_mfma_f32_16x16x32_bf16(afH, bf, accH, 0, 0, 0);
    }

    // gi pack (f16): R,Z regs (4 u32); N -> LDS own-slot; h0 master copy f32
    uint32_t gipR[2], gipZ[2];
    float hm[4];
    {
        float tbr[4], tbz[4], tbn[4], thi[4];
#pragma unroll
        for (int r = 0; r < 4; ++r) {
            int u = 16 * wsub + 4 * g + r;
            tbr[r] = bih[u] + bhh[u];
            tbz[r] = bih[128 + u] + bhh[128 + u];
            tbn[r] = bih[256 + u];
            thi[r] = binit[u];
        }
        gipR[0] = pkh2(accR[0] + tbr[0], accR[1] + tbr[1]);
        gipR[1] = pkh2(accR[2] + tbr[2], accR[3] + tbr[3]);
        gipZ[0] = pkh2(accZ[0] + tbz[0], accZ[1] + tbz[1]);
        gipZ[1] = pkh2(accZ[2] + tbz[2], accZ[3] + tbz[3]);
        uint2 gn;
        gn.x = pkh2(accN[0] + tbn[0], accN[1] + tbn[1]);
        gn.y = pkh2(accN[2] + tbn[2], accN[3] + tbn[3]);
        *(uint2*)(smem + OFF_GIN + tid * 8) = gn;        // own slot; no barrier needed
#pragma unroll
        for (int r = 0; r < 4; ++r)
            hm[r] = ftanhf(accH[r] + thi[r]);
    }
    __syncthreads();              // ctx reads done; h region reusable

    {   // h0 -> buf0
        uint2 pk;
        pk.x = cvtpk_bf16(hm[0], hm[1]);
        pk.y = cvtpk_bf16(hm[2], hm[3]);
        *(uint2*)(smem + OFF_H + (16 * mt + l15) * 256 + ((32 * wsub + 8 * g) ^ swz)) = pk;
    }
    __syncthreads();

    const int ub4 = (16 * wsub + 4 * g) * 4;     // gate-table byte offset
    const int um4 = (16 * jt + 4 * g) * 4;       // MLP-table byte offset

    // ---------------- recurrence: 49 iterations (t==TSTEPS = MLP-only tail) ----------------
    for (int t = 0; t <= TSTEPS; ++t) {
        const int rbuf = OFF_H + (t & 1) * HBUFSZ;         // h_t
        const int wbuf = OFF_H + ((t + 1) & 1) * HBUFSZ;   // h_{t+1}
        // anti-LICM: opaque zero keeps read-only LDS frags loop-variant (no 96-reg hoist)
        int tdep = 0;
        asm volatile("" : "+v"(tdep));
        const char* sm = smem + tdep;

        f32x4 aR, aZ, aN;
        f32x4 a1 = zero4;
        if (t < TSTEPS) {
            aR[0] = h2lo(gipR[0]); aR[1] = h2hi(gipR[0]);
            aR[2] = h2lo(gipR[1]); aR[3] = h2hi(gipR[1]);
            aZ[0] = h2lo(gipZ[0]); aZ[1] = h2hi(gipZ[0]);
            aZ[2] = h2lo(gipZ[1]); aZ[3] = h2hi(gipZ[1]);
            aN = *(const f32x4*)(sm + OFF_BHN + ub4);
#pragma unroll
            for (int kk = 0; kk < 4; ++kk) {
                const int cx = (64 * kk + 16 * g) ^ swz;
                short8 bf = *(const short8*)(sm + rbuf + (16 * mt + l15) * 256 + cx);
                short8 fR = *(const short8*)(sm + OFF_WR + u16 * 256 + cx);
                short8 fZ = *(const short8*)(sm + OFF_WZ + u16 * 256 + cx);
                short8 fN = *(const short8*)(sm + OFF_WN + u16 * 256 + cx);
                aR = __builtin_amdgcn_mfma_f32_16x16x32_bf16(fR, bf, aR, 0, 0, 0);
                aZ = __builtin_amdgcn_mfma_f32_16x16x32_bf16(fZ, bf, aZ, 0, 0, 0);
                aN = __builtin_amdgcn_mfma_f32_16x16x32_bf16(fN, bf, aN, 0, 0, 0);
            }
        }
        // MLP on h_t: waves 0..7 cover (jt x mrow); wave-uniform branch
        if (w < 8) {
#pragma unroll
            for (int kk = 0; kk < 4; ++kk) {
                const int cx = (64 * kk + 16 * g) ^ swz;
                short8 bfM = *(const short8*)(sm + rbuf + (16 * mrow + l15) * 256 + cx);
                short8 wf  = *(const short8*)(sm + OFF_W1 + (16 * jt + l15) * 256 + cx);
                a1 = __builtin_amdgcn_mfma_f32_16x16x32_bf16(wf, bfM, a1, 0, 0, 0);
            }
            f32x4 b1v = *(const f32x4*)(sm + OFF_TB1 + um4);
            f32x4 w2a = *(const f32x4*)(sm + OFF_TW2 + um4);
            f32x4 w2b = *(const f32x4*)(sm + OFF_TW2 + 256 + um4);
            float s0 = 0.f, s1 = 0.f;
#pragma unroll
            for (int r = 0; r < 4; ++r) {
                float hv = fmaxf(a1[r] + b1v[r], 0.f);
                s0 = fmaf(hv, w2a[r], s0);
                s1 = fmaf(hv, w2b[r], s1);
            }
            s0 += __shfl_xor(s0, 16, 64); s0 += __shfl_xor(s0, 32, 64);
            s1 += __shfl_xor(s1, 16, 64); s1 += __shfl_xor(s1, 32, 64);
            if (lane < 16) {
                f32x2 pw; pw.x = s0; pw.y = s1;
                *(f32x2*)(smem + OFF_PART + mrow * 512 + l15 * 32 + jt * 8) = pw;
            }
        }
        __syncthreads();          // barrier B: partials visible
        if (t > 0) {
            f32x4 q0 = *(const f32x4*)(smem + OFF_PART + mt * 512 + l15 * 32);
            f32x4 q1 = *(const f32x4*)(smem + OFF_PART + mt * 512 + l15 * 32 + 16);
            float pdx = (q0[0] + q0[2]) + (q1[0] + q1[2]) + b2c0;
            float pdy = (q0[1] + q0[3]) + (q1[1] + q1[3]) + b2c1;
            dx = pdx; dy = pdy;
            pos0v += pdx; pos1v += pdy;
            if (wsub == 0 && lane < 16) {
                f32x2 o2; o2.x = pos0v; o2.y = pos1v;
                *(f32x2*)(out + (size_t)(row0 + 16 * mt + l15) * (TSTEPS * 2) + 2 * (t - 1)) = o2;
            }
        }
        if (t < TSTEPS) {
            // gates: tables + gi_n from LDS; f16 halves inlined in fma (mix-fma)
            f32x4 wr0 = *(const f32x4*)(sm + OFF_WD +    0 + ub4);
            f32x4 wr1 = *(const f32x4*)(sm + OFF_WD +  512 + ub4);
            f32x4 wz0 = *(const f32x4*)(sm + OFF_WD + 1024 + ub4);
            f32x4 wz1 = *(const f32x4*)(sm + OFF_WD + 1536 + ub4);
            f32x4 wn0 = *(const f32x4*)(sm + OFF_WD + 2048 + ub4);
            f32x4 wn1 = *(const f32x4*)(sm + OFF_WD + 2560 + ub4);
            uint2 gn = *(const uint2*)(sm + OFF_GIN + tid * 8);
            uint32_t gnu[2] = {gn.x, gn.y};
#pragma unroll
            for (int r = 0; r < 4; ++r) {
                float rr  = fsigm(fmaf(dy, wr1[r], fmaf(dx, wr0[r], aR[r])));
                float zz  = fsigm(fmaf(dy, wz1[r], fmaf(dx, wz0[r], aZ[r])));
                float gnv = (r & 1) ? h2hi(gnu[r >> 1]) : h2lo(gnu[r >> 1]);
                float inn = fmaf(dy, wn1[r], fmaf(dx, wn0[r], gnv));
                float nn  = ftanhf(fmaf(rr, aN[r], inn));
                hm[r]     = fmaf(zz, hm[r] - nn, nn);
            }
            uint2 pk;
            pk.x = cvtpk_bf16(hm[0], hm[1]);
            pk.y = cvtpk_bf16(hm[2], hm[3]);
            *(uint2*)(smem + wbuf + (16 * mt + l15) * 256 + ((32 * wsub + 8 * g) ^ swz)) = pk;
        }
        __syncthreads();          // barrier A: h_{t+1} visible
    }
}

extern "C" void kernel_launch(void* const* d_in, const int* in_sizes, int n_in,
                              void* d_out, int out_size, void* d_ws, size_t ws_size,
                              hipStream_t stream) {
    (void)in_sizes; (void)n_in; (void)d_ws; (void)ws_size; (void)out_size;
    const float* ctx   = (const float*)d_in[0];
    const float* lv    = (const float*)d_in[1];
    const float* Winit = (const float*)d_in[2];
    const float* binit = (const float*)d_in[3];
    const float* Wih   = (const float*)d_in[4];
    const float* bih   = (const float*)d_in[5];
    const float* Whh   = (const float*)d_in[6];
    const float* bhh   = (const float*)d_in[7];
    const float* W1    = (const float*)d_in[8];
    const float* b1    = (const float*)d_in[9];
    const float* W2    = (const float*)d_in[10];
    const float* b2    = (const float*)d_in[11];
    float* out = (float*)d_out;

    hipFuncSetAttribute(reinterpret_cast<const void*>(dd_kernel),
                        hipFuncAttributeMaxDynamicSharedMemorySize, LDS_BYTES);
    dd_kernel<<<16384 / BM, TPB, LDS_BYTES, stream>>>(
        ctx, lv, Winit, binit, Wih, bih, Whh, bhh, W1, b1, W2, b2, out);
}